// Round 8
// baseline (119.602 us; speedup 1.0000x reference)
//
#include <hip/hip_runtime.h>

#define B_ 16
#define M_ 200
#define S_ 32
#define C_ 2048
#define V_ 32000
#define D_ 128
#define HOPS_ 3
#define NBLK 256
#define NTHR 1024

#define AG __HIP_MEMORY_SCOPE_AGENT
#define RLX __ATOMIC_RELAXED

// Flag-barrier pieces (R6-validated publish protocol: scope-stores for data,
// __syncthreads drains vmcnt, counter add, consumers read after wait).
__device__ __forceinline__ void arrive(unsigned* c) {
    __syncthreads();
    if (threadIdx.x == 0) __hip_atomic_fetch_add(c, 1u, RLX, AG);
}
__device__ __forceinline__ void wait_for(unsigned* c, unsigned n) {
    if (threadIdx.x == 0)
        while (__hip_atomic_load(c, RLX, AG) < n) __builtin_amdgcn_s_sleep(32);
    __syncthreads();
}

// ---------------------------------------------------------------------------
// K1: embedding bags grid-wide (verbatim R2-verified). 32 lanes per bag.
// ---------------------------------------------------------------------------
__global__ void k_embed(const int* __restrict__ stories, const int* __restrict__ query,
                        const float* __restrict__ embA,
                        float* __restrict__ m, float* __restrict__ u0) {
    int lane = threadIdx.x & 31;
    int sent = (blockIdx.x * 256 + threadIdx.x) >> 5;
    if (sent >= B_ * M_ + B_) return;
    const int* idx;
    float* dst;
    if (sent < B_ * M_) { idx = stories + sent * S_; dst = m + sent * D_; }
    else { int b = sent - B_ * M_; idx = query + b * S_; dst = u0 + b * D_; }
    float4 acc = {0.f, 0.f, 0.f, 0.f};
#pragma unroll 8
    for (int s = 0; s < S_; ++s) {
        const float4* row = (const float4*)(embA + (size_t)idx[s] * D_);
        float4 a = row[lane];
        acc.x += a.x; acc.y += a.y; acc.z += a.z; acc.w += a.w;
    }
    ((float4*)dst)[lane] = acc;
}

// ---------------------------------------------------------------------------
// K2: hops (blocks 0..15, m staged to LDS) + pv + logits, flag-synced.
// ---------------------------------------------------------------------------
__global__ void __launch_bounds__(NTHR) k_rest(
        const int* __restrict__ E, const int* __restrict__ cand,
        const float* __restrict__ embW, const float* __restrict__ Hw,
        const float* __restrict__ Hb, const float* __restrict__ m,
        const float* __restrict__ u0, float* __restrict__ uF,
        float* __restrict__ P, float* __restrict__ out, unsigned* __restrict__ bc) {
    const int t = threadIdx.x;
    const int blk = blockIdx.x;
    const int lane = t & 63;
    const int wave = t >> 6;

    __shared__ float sm[M_][D_];          // 102.4 KB (hop blocks only)
    __shared__ float su[D_];
    __shared__ float sattn[M_];
    __shared__ float sred[16 * D_];
    __shared__ float su_all[B_][132];     // padded: 2-way LDS aliasing only
    __shared__ float smx, ssum;

    // entry acquire: clear any stale lines from the previous replay
    __builtin_amdgcn_fence(__ATOMIC_ACQUIRE, "agent");

    if (blk < B_) {
        // ---------------- hops for batch b = blk ----------------
        const int b = blk;
        {   // stage m[b] -> LDS, coalesced float4
            const float4* src = (const float4*)(m + (size_t)b * M_ * D_);
            float4* dst = (float4*)sm;
            for (int j = t; j < M_ * D_ / 4; j += NTHR) dst[j] = src[j];
        }
        if (t < D_) su[t] = u0[b * D_ + t];
        __syncthreads();

        for (int hop = 0; hop < HOPS_; ++hop) {
            float2 uu = ((const float2*)su)[lane];
            for (int i = wave; i < M_; i += 16) {
                float2 mv = ((const float2*)sm[i])[lane];
                float p = mv.x * uu.x + mv.y * uu.y;
#pragma unroll
                for (int o = 32; o; o >>= 1) p += __shfl_xor(p, o);
                if (lane == 0) sattn[i] = p;
            }
            __syncthreads();
            if (wave == 0) {
                float mx = -3.0e38f;
                for (int i = lane; i < M_; i += 64) mx = fmaxf(mx, sattn[i]);
#pragma unroll
                for (int o = 32; o; o >>= 1) mx = fmaxf(mx, __shfl_xor(mx, o));
                float sm_ = 0.f;
                for (int i = lane; i < M_; i += 64) sm_ += expf(sattn[i] - mx);
#pragma unroll
                for (int o = 32; o; o >>= 1) sm_ += __shfl_xor(sm_, o);
                if (lane == 0) { smx = mx; ssum = sm_; }
            }
            __syncthreads();
            if (t < M_) sattn[t] = expf(sattn[t] - smx) * (1.f / ssum);
            __syncthreads();
            float2 oacc = {0.f, 0.f};
            for (int i = wave; i < M_; i += 16) {
                float a = sattn[i];
                float2 mv = ((const float2*)sm[i])[lane];
                oacc.x += a * mv.x; oacc.y += a * mv.y;
            }
            ((float2*)sred)[wave * 64 + lane] = oacc;
            __syncthreads();
            int d  = t >> 3;
            int k8 = t & 7;
            float tot = sred[k8 * D_ + d] + sred[(k8 + 8) * D_ + d];
            for (int k = k8; k < D_; k += 8) tot += Hw[d * D_ + k] * su[k];
#pragma unroll
            for (int o = 1; o < 8; o <<= 1) tot += __shfl_xor(tot, o);
            float un = Hb[d] + tot;
            __syncthreads();
            if (k8 == 0) su[d] = un;
            __syncthreads();
        }
        // publish final u[b] (write-through, no dirty L2 line)
        if (t < D_)
            __hip_atomic_store((unsigned*)(uF + b * D_ + t),
                               __builtin_bit_cast(unsigned, su[t]), RLX, AG);
        arrive(bc + 0);
    } else {
        // ---------------- warm L2 with this block's pv/logits data ----------------
        const float4* wsrc = (const float4*)(embW + (size_t)blk * 125 * D_);
        for (int i = t; i < 125 * D_ / 4; i += NTHR) {
            float4 w = wsrc[i]; asm volatile("" :: "v"(w.x));
        }
        int bb = blk >> 4, tile = blk & 15;
        const int4* cs = (const int4*)(cand + tile * 128 * S_);
        for (int i = t; i < 128 * S_ / 4; i += NTHR) {
            int4 x = cs[i]; asm volatile("" :: "v"(x.x));
        }
        const int4* es = (const int4*)(E + ((size_t)bb * C_ + tile * 128) * S_);
        for (int i = t; i < 128 * S_ / 4; i += NTHR) {
            int4 x = es[i]; asm volatile("" :: "v"(x.x));
        }
    }
    wait_for(bc + 0, B_);

    // ---------------- stage uF -> padded LDS (scope loads from LLC) ----------------
    {
        int b  = t >> 6;
        int d0 = (t & 63) * 2;
        unsigned long long vu = __hip_atomic_load(((unsigned long long*)uF) + t, RLX, AG);
        float2 f2 = __builtin_bit_cast(float2, vu);
        su_all[b][d0] = f2.x; su_all[b][d0 + 1] = f2.y;
    }
    __syncthreads();

    // ---------------- pv: P[v,b] for v in [blk*125, +125) ----------------
#pragma unroll
    for (int it = 0; it < 2; ++it) {
        int item = it * NTHR + t;
        if (item < 125 * B_) {
            int vi = item >> 4;
            int b  = item & 15;
            int v  = blk * 125 + vi;
            const float4* w  = (const float4*)(embW + (size_t)v * D_);
            const float4* uu = (const float4*)&su_all[b][0];
            float acc = 0.f;
#pragma unroll 8
            for (int j = 0; j < D_ / 4; ++j) {
                float4 a = w[j]; float4 x = uu[j];
                acc += a.x * x.x + a.y * x.y + a.z * x.z + a.w * x.w;
            }
            __hip_atomic_store((unsigned*)(P + (size_t)v * B_ + b),
                               __builtin_bit_cast(unsigned, acc), RLX, AG);
        }
    }
    arrive(bc + 128);
    wait_for(bc + 128, NBLK);

    // ---------------- logits: 8 lanes per (b,c) ----------------
    {
        int b    = blk >> 4;
        int tile = blk & 15;
        int c    = tile * 128 + (t >> 3);
        int q    = t & 7;
        const int4* src;
        if (q < 4) src = (const int4*)(cand + c * S_ + q * 8);
        else       src = (const int4*)(E + ((size_t)(b * C_ + c)) * S_ + (q - 4) * 8);
        float acc = 0.f;
#pragma unroll
        for (int j = 0; j < 2; ++j) {
            int4 w = src[j];
            acc += P[w.x * B_ + b] + P[w.y * B_ + b] + P[w.z * B_ + b] + P[w.w * B_ + b];
        }
        acc += __shfl_xor(acc, 1);
        acc += __shfl_xor(acc, 2);
        acc += __shfl_xor(acc, 4);
        if (q == 0) out[b * C_ + c] = acc;
    }
}

extern "C" void kernel_launch(void* const* d_in, const int* in_sizes, int n_in,
                              void* d_out, int out_size, void* d_ws, size_t ws_size,
                              hipStream_t stream) {
    const int*   stories = (const int*)d_in[0];
    const int*   query   = (const int*)d_in[1];
    const int*   E       = (const int*)d_in[2];
    const int*   cand    = (const int*)d_in[3];
    const float* embA    = (const float*)d_in[4];
    const float* embW    = (const float*)d_in[5];
    const float* Hw      = (const float*)d_in[6];
    const float* Hb      = (const float*)d_in[7];
    float* out = (float*)d_out;

    char* ws = (char*)d_ws;
    unsigned* bc = (unsigned*)ws;                       // counters at uint idx 0, 128
    float* u0 = (float*)(ws + 4096);                    // 8 KB
    float* uF = (float*)(ws + 12288);                   // 8 KB
    float* m  = (float*)(ws + 24576);                   // 1.6 MB
    float* P  = (float*)(ws + 24576 + (size_t)B_ * M_ * D_ * 4);  // 2.0 MB

    (void)hipMemsetAsync(ws, 0, 1024, stream);          // zero barrier counters

    hipLaunchKernelGGL(k_embed, dim3((B_ * M_ + B_) * 32 / 256), dim3(256), 0, stream,
                       stories, query, embA, m, u0);

    void* args[] = { (void*)&E, (void*)&cand, (void*)&embW, (void*)&Hw, (void*)&Hb,
                     (void*)&m, (void*)&u0, (void*)&uF, (void*)&P, (void*)&out,
                     (void*)&bc };
    (void)hipLaunchCooperativeKernel((const void*)k_rest, dim3(NBLK), dim3(NTHR),
                                     args, 0, stream);
}

// Round 9
// 87.806 us; speedup vs baseline: 1.3621x; 1.3621x over previous
//
#include <hip/hip_runtime.h>

#define B_ 16
#define M_ 200
#define S_ 32
#define C_ 2048
#define V_ 32000
#define D_ 128
#define HOPS_ 3

// ---------------------------------------------------------------------------
// K1: embedding bags grid-wide (R2-verified). 32 lanes per bag, float4 rows.
//   m[b,i,:] = sum_s embA[stories[b,i,s],:]   (bags 0..3199)
//   u0[b,:]  = sum_s embA[query[b,s],:]       (bags 3200..3215)
// ---------------------------------------------------------------------------
__global__ void k_embed(const int* __restrict__ stories, const int* __restrict__ query,
                        const float* __restrict__ embA,
                        float* __restrict__ m, float* __restrict__ u0) {
    int lane = threadIdx.x & 31;
    int sent = (blockIdx.x * 256 + threadIdx.x) >> 5;
    if (sent >= B_ * M_ + B_) return;
    const int* idx;
    float* dst;
    if (sent < B_ * M_) { idx = stories + sent * S_; dst = m + sent * D_; }
    else { int b = sent - B_ * M_; idx = query + b * S_; dst = u0 + b * D_; }
    float4 acc = {0.f, 0.f, 0.f, 0.f};
#pragma unroll 8
    for (int s = 0; s < S_; ++s) {
        const float4* row = (const float4*)(embA + (size_t)idx[s] * D_);
        float4 a = row[lane];
        acc.x += a.x; acc.y += a.y; acc.z += a.z; acc.w += a.w;
    }
    ((float4*)dst)[lane] = acc;
}

// ---------------------------------------------------------------------------
// K2: hops. One 1024-thread block per batch; m[b] staged into LDS (102.4 KB),
// all 3 hops run from LDS (R7/R8-verified numerics). Writes uF (plain store).
// ---------------------------------------------------------------------------
__global__ void __launch_bounds__(1024) k_hops(
        const float* __restrict__ m, const float* __restrict__ u0,
        const float* __restrict__ Hw, const float* __restrict__ Hb,
        float* __restrict__ uF) {
    const int b = blockIdx.x;
    const int t = threadIdx.x;
    const int lane = t & 63;
    const int wave = t >> 6;                 // 16 waves

    __shared__ float sm[M_][D_];             // 102.4 KB
    __shared__ float su[D_];
    __shared__ float sattn[M_];
    __shared__ float sred[16 * D_];
    __shared__ float smx, ssum;

    {   // stage m[b] -> LDS, coalesced float4
        const float4* src = (const float4*)(m + (size_t)b * M_ * D_);
        float4* dst = (float4*)sm;
        for (int j = t; j < M_ * D_ / 4; j += 1024) dst[j] = src[j];
    }
    if (t < D_) su[t] = u0[b * D_ + t];
    __syncthreads();

    for (int hop = 0; hop < HOPS_; ++hop) {
        // scores: attn[i] = sm[i,:] . su   (one row per wave, shfl reduce)
        float2 uu = ((const float2*)su)[lane];
        for (int i = wave; i < M_; i += 16) {
            float2 mv = ((const float2*)sm[i])[lane];
            float p = mv.x * uu.x + mv.y * uu.y;
#pragma unroll
            for (int o = 32; o; o >>= 1) p += __shfl_xor(p, o);
            if (lane == 0) sattn[i] = p;
        }
        __syncthreads();
        // softmax max/sum by wave 0
        if (wave == 0) {
            float mx = -3.0e38f;
            for (int i = lane; i < M_; i += 64) mx = fmaxf(mx, sattn[i]);
#pragma unroll
            for (int o = 32; o; o >>= 1) mx = fmaxf(mx, __shfl_xor(mx, o));
            float sm_ = 0.f;
            for (int i = lane; i < M_; i += 64) sm_ += expf(sattn[i] - mx);
#pragma unroll
            for (int o = 32; o; o >>= 1) sm_ += __shfl_xor(sm_, o);
            if (lane == 0) { smx = mx; ssum = sm_; }
        }
        __syncthreads();
        if (t < M_) sattn[t] = expf(sattn[t] - smx) * (1.f / ssum);
        __syncthreads();
        // o[d] = sum_i attn[i]*sm[i][d]  (per-wave partials)
        float2 oacc = {0.f, 0.f};
        for (int i = wave; i < M_; i += 16) {
            float a = sattn[i];
            float2 mv = ((const float2*)sm[i])[lane];
            oacc.x += a * mv.x; oacc.y += a * mv.y;
        }
        ((float2*)sred)[wave * 64 + lane] = oacc;
        __syncthreads();
        // u_new[d] = Hb[d] + o[d] + sum_k Hw[d,k]*su[k]   (8 lanes per d)
        int d  = t >> 3;
        int k8 = t & 7;
        float tot = sred[k8 * D_ + d] + sred[(k8 + 8) * D_ + d];
        for (int k = k8; k < D_; k += 8) tot += Hw[d * D_ + k] * su[k];
#pragma unroll
        for (int o = 1; o < 8; o <<= 1) tot += __shfl_xor(tot, o);
        float un = Hb[d] + tot;
        __syncthreads();
        if (k8 == 0) su[d] = un;
        __syncthreads();
    }
    if (t < D_) uF[b * D_ + t] = su[t];
}

// ---------------------------------------------------------------------------
// K3: P[v,b] = dot(uF[b,:], embW[v,:])   (R2-verified; [V][B] layout)
// ---------------------------------------------------------------------------
__global__ void k_pv(const float* __restrict__ uF, const float* __restrict__ embW,
                     float* __restrict__ P) {
    int g = blockIdx.x * 256 + threadIdx.x;   // g = v*16 + b
    int b = g & (B_ - 1);
    int v = g >> 4;
    const float4* w  = (const float4*)(embW + (size_t)v * D_);
    const float4* uu = (const float4*)(uF + b * D_);
    float acc = 0.f;
#pragma unroll 8
    for (int j = 0; j < D_ / 4; ++j) {
        float4 a = w[j]; float4 x = uu[j];
        acc += a.x * x.x + a.y * x.y + a.z * x.z + a.w * x.w;
    }
    P[v * B_ + b] = acc;
}

// ---------------------------------------------------------------------------
// K4: logits[b,c] = sum_s P[cand[c,s],b] + sum_s P[E[b,c,s],b]
// (R2-verified: 4 lanes per (b,c), shfl combine)
// ---------------------------------------------------------------------------
__global__ void k_logits(const int* __restrict__ cand, const int* __restrict__ E,
                         const float* __restrict__ P, float* __restrict__ out) {
    int g4 = blockIdx.x * 256 + threadIdx.x;  // (b*C + c)*4 + q
    int q = g4 & 3;
    int g = g4 >> 2;
    int c = g & (C_ - 1);
    int b = g >> 11;
    const int4* cs = (const int4*)(cand + c * S_ + q * 8);
    const int4* es = (const int4*)(E + (size_t)g * S_ + q * 8);
    float acc = 0.f;
#pragma unroll
    for (int j = 0; j < 2; ++j) {
        int4 wv = cs[j];
        acc += P[wv.x * B_ + b] + P[wv.y * B_ + b] + P[wv.z * B_ + b] + P[wv.w * B_ + b];
        int4 ev = es[j];
        acc += P[ev.x * B_ + b] + P[ev.y * B_ + b] + P[ev.z * B_ + b] + P[ev.w * B_ + b];
    }
    acc += __shfl_xor(acc, 1);
    acc += __shfl_xor(acc, 2);
    if (q == 0) out[g] = acc;
}

extern "C" void kernel_launch(void* const* d_in, const int* in_sizes, int n_in,
                              void* d_out, int out_size, void* d_ws, size_t ws_size,
                              hipStream_t stream) {
    const int*   stories = (const int*)d_in[0];
    const int*   query   = (const int*)d_in[1];
    const int*   E       = (const int*)d_in[2];
    const int*   cand    = (const int*)d_in[3];
    const float* embA    = (const float*)d_in[4];
    const float* embW    = (const float*)d_in[5];
    const float* Hw      = (const float*)d_in[6];
    const float* Hb      = (const float*)d_in[7];
    float* out = (float*)d_out;

    char* ws = (char*)d_ws;
    float* u0 = (float*)ws;                                   //   8 KB
    float* uF = (float*)(ws + 8192);                          //   8 KB
    float* m  = (float*)(ws + 16384);                         // 1.6 MB
    float* P  = (float*)(ws + 16384 + (size_t)B_ * M_ * D_ * 4);  // 2.0 MB

    hipLaunchKernelGGL(k_embed,  dim3((B_ * M_ + B_) * 32 / 256), dim3(256), 0, stream,
                       stories, query, embA, m, u0);
    hipLaunchKernelGGL(k_hops,   dim3(B_), dim3(1024), 0, stream, m, u0, Hw, Hb, uF);
    hipLaunchKernelGGL(k_pv,     dim3((B_ * V_) / 256), dim3(256), 0, stream, uF, embW, P);
    hipLaunchKernelGGL(k_logits, dim3((B_ * C_ * 4) / 256), dim3(256), 0, stream,
                       cand, E, P, out);
}

// Round 10
// 59.788 us; speedup vs baseline: 2.0004x; 1.4686x over previous
//
#include <hip/hip_runtime.h>

#define B_ 16
#define M_ 200
#define S_ 32
#define C_ 2048
#define V_ 32000
#define D_ 128
#define HOPS_ 3

// ---------------------------------------------------------------------------
// K1: embedding bags grid-wide (R2-verified). 32 lanes per bag, float4 rows.
// ---------------------------------------------------------------------------
__global__ void k_embed(const int* __restrict__ stories, const int* __restrict__ query,
                        const float* __restrict__ embA,
                        float* __restrict__ m, float* __restrict__ u0) {
    int lane = threadIdx.x & 31;
    int sent = (blockIdx.x * 256 + threadIdx.x) >> 5;
    if (sent >= B_ * M_ + B_) return;
    const int* idx;
    float* dst;
    if (sent < B_ * M_) { idx = stories + sent * S_; dst = m + sent * D_; }
    else { int b = sent - B_ * M_; idx = query + b * S_; dst = u0 + b * D_; }
    float4 acc = {0.f, 0.f, 0.f, 0.f};
#pragma unroll 8
    for (int s = 0; s < S_; ++s) {
        const float4* row = (const float4*)(embA + (size_t)idx[s] * D_);
        float4 a = row[lane];
        acc.x += a.x; acc.y += a.y; acc.z += a.z; acc.w += a.w;
    }
    ((float4*)dst)[lane] = acc;
}

// ---------------------------------------------------------------------------
// K2: hops. One 1024-thread block per batch; m[b] staged into LDS (102.4 KB),
// all 3 hops run from LDS (R7/R8/R9-verified numerics).
// ---------------------------------------------------------------------------
__global__ void __launch_bounds__(1024) k_hops(
        const float* __restrict__ m, const float* __restrict__ u0,
        const float* __restrict__ Hw, const float* __restrict__ Hb,
        float* __restrict__ uF) {
    const int b = blockIdx.x;
    const int t = threadIdx.x;
    const int lane = t & 63;
    const int wave = t >> 6;                 // 16 waves

    __shared__ float sm[M_][D_];             // 102.4 KB
    __shared__ float su[D_];
    __shared__ float sattn[M_];
    __shared__ float sred[16 * D_];
    __shared__ float smx, ssum;

    {   // stage m[b] -> LDS, coalesced float4
        const float4* src = (const float4*)(m + (size_t)b * M_ * D_);
        float4* dst = (float4*)sm;
        for (int j = t; j < M_ * D_ / 4; j += 1024) dst[j] = src[j];
    }
    if (t < D_) su[t] = u0[b * D_ + t];
    __syncthreads();

    for (int hop = 0; hop < HOPS_; ++hop) {
        float2 uu = ((const float2*)su)[lane];
        for (int i = wave; i < M_; i += 16) {
            float2 mv = ((const float2*)sm[i])[lane];
            float p = mv.x * uu.x + mv.y * uu.y;
#pragma unroll
            for (int o = 32; o; o >>= 1) p += __shfl_xor(p, o);
            if (lane == 0) sattn[i] = p;
        }
        __syncthreads();
        if (wave == 0) {
            float mx = -3.0e38f;
            for (int i = lane; i < M_; i += 64) mx = fmaxf(mx, sattn[i]);
#pragma unroll
            for (int o = 32; o; o >>= 1) mx = fmaxf(mx, __shfl_xor(mx, o));
            float sm_ = 0.f;
            for (int i = lane; i < M_; i += 64) sm_ += expf(sattn[i] - mx);
#pragma unroll
            for (int o = 32; o; o >>= 1) sm_ += __shfl_xor(sm_, o);
            if (lane == 0) { smx = mx; ssum = sm_; }
        }
        __syncthreads();
        if (t < M_) sattn[t] = expf(sattn[t] - smx) * (1.f / ssum);
        __syncthreads();
        float2 oacc = {0.f, 0.f};
        for (int i = wave; i < M_; i += 16) {
            float a = sattn[i];
            float2 mv = ((const float2*)sm[i])[lane];
            oacc.x += a * mv.x; oacc.y += a * mv.y;
        }
        ((float2*)sred)[wave * 64 + lane] = oacc;
        __syncthreads();
        int d  = t >> 3;
        int k8 = t & 7;
        float tot = sred[k8 * D_ + d] + sred[(k8 + 8) * D_ + d];
        for (int k = k8; k < D_; k += 8) tot += Hw[d * D_ + k] * su[k];
#pragma unroll
        for (int o = 1; o < 8; o <<= 1) tot += __shfl_xor(tot, o);
        float un = Hb[d] + tot;
        __syncthreads();
        if (k8 == 0) su[d] = un;
        __syncthreads();
    }
    if (t < D_) uF[b * D_ + t] = su[t];
}

// ---------------------------------------------------------------------------
// K3 (rewritten): P[v,b] = dot(uF[b,:], embW[v,:]).
// Thread = (v, quarter q): streams 128 B of embW once; acc[16] in VGPRs;
// u fragments from bank-padded LDS (slot b*36+q*9+j -> q hits banks x,x+4,
// x+8,x+12: conflict-free); 4-lane shfl butterfly; lane q stores float4.
// ---------------------------------------------------------------------------
__global__ void __launch_bounds__(256) k_pv(
        const float* __restrict__ uF, const float* __restrict__ embW,
        float* __restrict__ P) {
    const int t = threadIdx.x;
    const int gtid = blockIdx.x * 256 + t;
    const int v = gtid >> 2;
    const int q = t & 3;

    __shared__ float4 su4[16 * 36];          // padded u: slot = b*36 + q*9 + j
    {
#pragma unroll
        for (int it = 0; it < 2; ++it) {
            int f = t + it * 256;            // float4 index into uF (512 total)
            int b = f >> 5, k = f & 31;
            su4[b * 36 + (k >> 3) * 9 + (k & 7)] = ((const float4*)uF)[f];
        }
    }
    __syncthreads();

    const float4* w = (const float4*)(embW + (size_t)v * D_) + q * 8;
    float acc[16];
#pragma unroll
    for (int b = 0; b < 16; ++b) acc[b] = 0.f;
#pragma unroll
    for (int j = 0; j < 8; ++j) {
        float4 a = w[j];
#pragma unroll
        for (int b = 0; b < 16; ++b) {
            float4 x = su4[b * 36 + q * 9 + j];
            acc[b] += a.x * x.x + a.y * x.y + a.z * x.z + a.w * x.w;
        }
    }
    // combine the 4 q-partials (lanes v*4..v*4+3 of the wave)
#pragma unroll
    for (int b = 0; b < 16; ++b) {
        acc[b] += __shfl_xor(acc[b], 1);
        acc[b] += __shfl_xor(acc[b], 2);
    }
    // lane q writes batches 4q..4q+3 -> coalesced float4 stores
    float4 o;
    o.x = acc[q * 4 + 0]; o.y = acc[q * 4 + 1];
    o.z = acc[q * 4 + 2]; o.w = acc[q * 4 + 3];
    ((float4*)(P + (size_t)v * B_))[q] = o;
}

// ---------------------------------------------------------------------------
// K4: logits[b,c] = sum_s P[cand[c,s],b] + sum_s P[E[b,c,s],b]  (R2-verified)
// ---------------------------------------------------------------------------
__global__ void k_logits(const int* __restrict__ cand, const int* __restrict__ E,
                         const float* __restrict__ P, float* __restrict__ out) {
    int g4 = blockIdx.x * 256 + threadIdx.x;  // (b*C + c)*4 + q
    int q = g4 & 3;
    int g = g4 >> 2;
    int c = g & (C_ - 1);
    int b = g >> 11;
    const int4* cs = (const int4*)(cand + c * S_ + q * 8);
    const int4* es = (const int4*)(E + (size_t)g * S_ + q * 8);
    float acc = 0.f;
#pragma unroll
    for (int j = 0; j < 2; ++j) {
        int4 wv = cs[j];
        acc += P[wv.x * B_ + b] + P[wv.y * B_ + b] + P[wv.z * B_ + b] + P[wv.w * B_ + b];
        int4 ev = es[j];
        acc += P[ev.x * B_ + b] + P[ev.y * B_ + b] + P[ev.z * B_ + b] + P[ev.w * B_ + b];
    }
    acc += __shfl_xor(acc, 1);
    acc += __shfl_xor(acc, 2);
    if (q == 0) out[g] = acc;
}

extern "C" void kernel_launch(void* const* d_in, const int* in_sizes, int n_in,
                              void* d_out, int out_size, void* d_ws, size_t ws_size,
                              hipStream_t stream) {
    const int*   stories = (const int*)d_in[0];
    const int*   query   = (const int*)d_in[1];
    const int*   E       = (const int*)d_in[2];
    const int*   cand    = (const int*)d_in[3];
    const float* embA    = (const float*)d_in[4];
    const float* embW    = (const float*)d_in[5];
    const float* Hw      = (const float*)d_in[6];
    const float* Hb      = (const float*)d_in[7];
    float* out = (float*)d_out;

    char* ws = (char*)d_ws;
    float* u0 = (float*)ws;                                   //   8 KB
    float* uF = (float*)(ws + 8192);                          //   8 KB
    float* m  = (float*)(ws + 16384);                         // 1.6 MB
    float* P  = (float*)(ws + 16384 + (size_t)B_ * M_ * D_ * 4);  // 2.0 MB

    hipLaunchKernelGGL(k_embed,  dim3((B_ * M_ + B_) * 32 / 256), dim3(256), 0, stream,
                       stories, query, embA, m, u0);
    hipLaunchKernelGGL(k_hops,   dim3(B_), dim3(1024), 0, stream, m, u0, Hw, Hb, uF);
    hipLaunchKernelGGL(k_pv,     dim3(V_ * 4 / 256), dim3(256), 0, stream, uF, embW, P);
    hipLaunchKernelGGL(k_logits, dim3((B_ * C_ * 4) / 256), dim3(256), 0, stream,
                       cand, E, P, out);
}